// Round 2
// baseline (6532.619 us; speedup 1.0000x reference)
//
#include <hip/hip_runtime.h>

#define FLT_MAX_C 3.402823466e+38f

// ---------------- GEMM: C = [relu](A[M,K] @ W[K,N] + b[N]) ----------------
// BM=BN=128, BK=8, 256 threads, 8x8 micro-tile per thread. All dims used are
// multiples of the tile sizes, so no bounds checks.
template<bool RELU>
__global__ __launch_bounds__(256) void gemm_bias(
    const float* __restrict__ A, const float* __restrict__ W,
    const float* __restrict__ bias, float* __restrict__ C,
    int M, int K, int N)
{
    __shared__ float As[8][128];
    __shared__ float Bs[8][128];
    const int tid = threadIdx.x;
    const int bm = blockIdx.y << 7;
    const int bn = blockIdx.x << 7;

    const int la_row = tid >> 1;          // 0..127
    const int la_k   = (tid & 1) << 2;    // 0 or 4
    const int lb_row = tid >> 5;          // 0..7
    const int lb_col = (tid & 31) << 2;   // 0..124
    const int tm = (tid >> 4) << 3;       // 0..120
    const int tn = (tid & 15) << 3;       // 0..120

    float acc[8][8];
    #pragma unroll
    for (int i = 0; i < 8; ++i)
        #pragma unroll
        for (int j = 0; j < 8; ++j) acc[i][j] = 0.f;

    const float* aptr = A + (size_t)(bm + la_row) * K + la_k;
    const float* bptr = W + (size_t)lb_row * N + bn + lb_col;

    for (int k0 = 0; k0 < K; k0 += 8) {
        float4 av = *(const float4*)(aptr + k0);
        float4 bv = *(const float4*)(bptr + (size_t)k0 * N);
        __syncthreads();
        As[la_k + 0][la_row] = av.x;
        As[la_k + 1][la_row] = av.y;
        As[la_k + 2][la_row] = av.z;
        As[la_k + 3][la_row] = av.w;
        *(float4*)(&Bs[lb_row][lb_col]) = bv;
        __syncthreads();
        #pragma unroll
        for (int kk = 0; kk < 8; ++kk) {
            float a[8], b[8];
            *(float4*)(a)     = *(const float4*)(&As[kk][tm]);
            *(float4*)(a + 4) = *(const float4*)(&As[kk][tm + 4]);
            *(float4*)(b)     = *(const float4*)(&Bs[kk][tn]);
            *(float4*)(b + 4) = *(const float4*)(&Bs[kk][tn + 4]);
            #pragma unroll
            for (int i = 0; i < 8; ++i)
                #pragma unroll
                for (int j = 0; j < 8; ++j)
                    acc[i][j] = fmaf(a[i], b[j], acc[i][j]);
        }
    }

    float bv[8];
    #pragma unroll
    for (int j = 0; j < 8; ++j) bv[j] = bias[bn + tn + j];

    #pragma unroll
    for (int i = 0; i < 8; ++i) {
        float* cp = C + (size_t)(bm + tm + i) * N + bn + tn;
        #pragma unroll
        for (int j = 0; j < 8; j += 4) {
            float4 v;
            v.x = acc[i][j + 0] + bv[j + 0];
            v.y = acc[i][j + 1] + bv[j + 1];
            v.z = acc[i][j + 2] + bv[j + 2];
            v.w = acc[i][j + 3] + bv[j + 3];
            if (RELU) {
                v.x = fmaxf(v.x, 0.f); v.y = fmaxf(v.y, 0.f);
                v.z = fmaxf(v.z, 0.f); v.w = fmaxf(v.w, 0.f);
            }
            *(float4*)(cp + j) = v;
        }
    }
}

// ---------------- codebook squared norms ----------------
__global__ __launch_bounds__(256) void cbsq_kernel(
    const float* __restrict__ cb, float* __restrict__ cbsq)
{
    int k = blockIdx.x * 256 + threadIdx.x;  // grid 4x256 = 1024 exact
    const float* r = cb + ((size_t)k << 7);
    float s = 0.f;
    #pragma unroll 8
    for (int d = 0; d < 128; ++d) s = fmaf(r[d], r[d], s);
    cbsq[k] = s;
}

// ---------------- residual quantization ----------------
// Block = 256 threads = 4 waves; block handles 16 rows (4 per wave).
// dist = (rr + cb_sq[k]) - 2*(r . c_k), matching the reference formula.
// Lane-local code = chunk*64 + lane; first-min tie-break preserved.
__global__ __launch_bounds__(256) void quant_kernel(
    const float* __restrict__ z, const float* __restrict__ cb,
    const float* __restrict__ cbsq, float* __restrict__ zhat,
    float* __restrict__ codes)
{
    __shared__ float rs[16][128];     // residues for 16 rows
    __shared__ float cbl[64][132];    // codebook chunk, padded pitch (132)
    __shared__ float cbsq_l[1024];

    const int tid  = threadIdx.x;
    const int lane = tid & 63;
    const int wv   = tid >> 6;        // wave 0..3, owns rows wv*4..wv*4+3
    const int row0 = blockIdx.x << 4; // 16 rows per block

    // load z rows -> rs (residue starts as z)
    #pragma unroll
    for (int i = 0; i < 2; ++i) {
        int f = tid + (i << 8);
        ((float4*)rs)[f] = ((const float4*)(z + ((size_t)row0 << 7)))[f];
    }
    #pragma unroll
    for (int i = 0; i < 4; ++i) cbsq_l[tid + (i << 8)] = cbsq[tid + (i << 8)];
    __syncthreads();

    for (int t = 0; t < 3; ++t) {
        // rr per owned row
        float rr_[4];
        #pragma unroll
        for (int j = 0; j < 4; ++j) {
            const float* rp = rs[wv * 4 + j];
            float v0 = rp[lane * 2], v1 = rp[lane * 2 + 1];
            float p = v0 * v0 + v1 * v1;
            #pragma unroll
            for (int off = 32; off >= 1; off >>= 1) p += __shfl_xor(p, off);
            rr_[j] = p;
        }

        float best_d[4] = {FLT_MAX_C, FLT_MAX_C, FLT_MAX_C, FLT_MAX_C};
        int   best_i[4] = {0, 0, 0, 0};

        for (int c = 0; c < 16; ++c) {
            __syncthreads();   // prior chunk reads done before overwrite
            // stage 64 codes x 128 dims
            #pragma unroll
            for (int i = 0; i < 8; ++i) {
                int f    = tid + (i << 8);   // float4 id 0..2047
                int code = f >> 5;           // 32 float4 per code row
                int d4   = f & 31;
                float4 v = ((const float4*)(cb + ((size_t)(c * 64 + code) << 7)))[d4];
                *(float4*)(&cbl[code][d4 << 2]) = v;
            }
            __syncthreads();

            const int k = c * 64 + lane;
            float acc0 = 0.f, acc1 = 0.f, acc2 = 0.f, acc3 = 0.f;
            #pragma unroll 8
            for (int d4 = 0; d4 < 32; ++d4) {
                float4 cv = *(const float4*)(&cbl[lane][d4 << 2]);
                float4 r0 = *(const float4*)(&rs[wv * 4 + 0][d4 << 2]);
                float4 r1 = *(const float4*)(&rs[wv * 4 + 1][d4 << 2]);
                float4 r2 = *(const float4*)(&rs[wv * 4 + 2][d4 << 2]);
                float4 r3 = *(const float4*)(&rs[wv * 4 + 3][d4 << 2]);
                acc0 = fmaf(r0.x, cv.x, acc0); acc0 = fmaf(r0.y, cv.y, acc0);
                acc0 = fmaf(r0.z, cv.z, acc0); acc0 = fmaf(r0.w, cv.w, acc0);
                acc1 = fmaf(r1.x, cv.x, acc1); acc1 = fmaf(r1.y, cv.y, acc1);
                acc1 = fmaf(r1.z, cv.z, acc1); acc1 = fmaf(r1.w, cv.w, acc1);
                acc2 = fmaf(r2.x, cv.x, acc2); acc2 = fmaf(r2.y, cv.y, acc2);
                acc2 = fmaf(r2.z, cv.z, acc2); acc2 = fmaf(r2.w, cv.w, acc2);
                acc3 = fmaf(r3.x, cv.x, acc3); acc3 = fmaf(r3.y, cv.y, acc3);
                acc3 = fmaf(r3.z, cv.z, acc3); acc3 = fmaf(r3.w, cv.w, acc3);
            }
            float dd[4];
            dd[0] = (rr_[0] + cbsq_l[k]) - 2.f * acc0;
            dd[1] = (rr_[1] + cbsq_l[k]) - 2.f * acc1;
            dd[2] = (rr_[2] + cbsq_l[k]) - 2.f * acc2;
            dd[3] = (rr_[3] + cbsq_l[k]) - 2.f * acc3;
            #pragma unroll
            for (int j = 0; j < 4; ++j)
                if (dd[j] < best_d[j]) { best_d[j] = dd[j]; best_i[j] = k; }
        }

        // wave argmin reduce (prefer lower index on ties = numpy first-min)
        #pragma unroll
        for (int j = 0; j < 4; ++j) {
            float d = best_d[j]; int bi = best_i[j];
            #pragma unroll
            for (int off = 32; off >= 1; off >>= 1) {
                float od = __shfl_xor(d, off);
                int   oi = __shfl_xor(bi, off);
                if (od < d || (od == d && oi < bi)) { d = od; bi = oi; }
            }
            best_d[j] = d; best_i[j] = bi;
        }

        // write codes (as float) + update residue
        #pragma unroll
        for (int j = 0; j < 4; ++j) {
            int row = row0 + wv * 4 + j;
            if (lane == 0) codes[(size_t)row * 3 + t] = (float)best_i[j];
            const float* cvec = cb + ((size_t)best_i[j] << 7);
            rs[wv * 4 + j][lane * 2]     -= cvec[lane * 2];
            rs[wv * 4 + j][lane * 2 + 1] -= cvec[lane * 2 + 1];
        }
    }

    __syncthreads();  // rs updated by owning waves; read flat below
    // zhat = z - residue_final
    #pragma unroll
    for (int i = 0; i < 2; ++i) {
        int f = tid + (i << 8);
        float4 zv = ((const float4*)(z + ((size_t)row0 << 7)))[f];
        float4 rv = ((float4*)rs)[f];
        float4 o;
        o.x = zv.x - rv.x; o.y = zv.y - rv.y;
        o.z = zv.z - rv.z; o.w = zv.w - rv.w;
        ((float4*)(zhat + ((size_t)row0 << 7)))[f] = o;
    }
}

extern "C" void kernel_launch(void* const* d_in, const int* in_sizes, int n_in,
                              void* d_out, int out_size, void* d_ws, size_t ws_size,
                              hipStream_t stream)
{
    const float* x   = (const float*)d_in[0];
    const float* eW1 = (const float*)d_in[1];
    const float* eb1 = (const float*)d_in[2];
    const float* eW2 = (const float*)d_in[3];
    const float* eb2 = (const float*)d_in[4];
    const float* eW3 = (const float*)d_in[5];
    const float* eb3 = (const float*)d_in[6];
    const float* eW4 = (const float*)d_in[7];
    const float* eb4 = (const float*)d_in[8];
    const float* dW1 = (const float*)d_in[9];
    const float* db1 = (const float*)d_in[10];
    const float* dW2 = (const float*)d_in[11];
    const float* db2 = (const float*)d_in[12];
    const float* dW3 = (const float*)d_in[13];
    const float* db3 = (const float*)d_in[14];
    const float* dW4 = (const float*)d_in[15];
    const float* db4 = (const float*)d_in[16];
    const float* cb  = (const float*)d_in[17];

    float* out   = (float*)d_out;
    float* codes = out + (size_t)32768 * 768;

    // ---- choose batch chunk size from ws_size (deterministic: ws_size is
    // constant across calls). Per-chunk scratch = mc*3840 + 1024 floats. ----
    int mc = 32768;
    while (mc > 1024) {
        size_t need = ((size_t)mc * 3840 + 1024) * sizeof(float);
        if (need <= ws_size) break;
        mc >>= 1;
    }

    float* ws = (float*)d_ws;
    float* R1  = ws;                             // mc x 2048
    float* R2  = R1 + (size_t)mc * 2048;         // mc x 1024
    float* R3  = R2 + (size_t)mc * 1024;         // mc x 512
    float* RZ  = R3 + (size_t)mc * 512;          // mc x 128
    float* RZH = RZ + (size_t)mc * 128;          // mc x 128
    float* sq  = RZH + (size_t)mc * 128;         // 1024

    cbsq_kernel<<<4, 256, 0, stream>>>(cb, sq);

    const int mg = mc >> 7;  // GEMM grid.y per chunk
    for (int r0 = 0; r0 < 32768; r0 += mc) {
        const float* xi     = x     + (size_t)r0 * 768;
        float*       outi   = out   + (size_t)r0 * 768;
        float*       codesi = codes + (size_t)r0 * 3;
        // encoder
        gemm_bias<true ><<<dim3(16, mg), 256, 0, stream>>>(xi, eW1, eb1, R1, mc, 768,  2048);
        gemm_bias<true ><<<dim3( 8, mg), 256, 0, stream>>>(R1, eW2, eb2, R2, mc, 2048, 1024);
        gemm_bias<true ><<<dim3( 4, mg), 256, 0, stream>>>(R2, eW3, eb3, R3, mc, 1024, 512);
        gemm_bias<false><<<dim3( 1, mg), 256, 0, stream>>>(R3, eW4, eb4, RZ, mc, 512,  128);
        // residual quantization
        quant_kernel<<<mc >> 4, 256, 0, stream>>>(RZ, cb, sq, RZH, codesi);
        // decoder (forward path uses z_hat: straight-through estimator)
        gemm_bias<true ><<<dim3(16, mg), 256, 0, stream>>>(RZH, dW1, db1, R1, mc, 128,  2048);
        gemm_bias<true ><<<dim3( 8, mg), 256, 0, stream>>>(R1,  dW2, db2, R2, mc, 2048, 1024);
        gemm_bias<true ><<<dim3( 4, mg), 256, 0, stream>>>(R2,  dW3, db3, R3, mc, 1024, 512);
        gemm_bias<false><<<dim3( 6, mg), 256, 0, stream>>>(R3,  dW4, db4, outi, mc, 512, 768);
    }
}

// Round 3
// 4348.246 us; speedup vs baseline: 1.5024x; 1.5024x over previous
//
#include <hip/hip_runtime.h>

#define FLT_MAX_C 3.402823466e+38f

typedef __attribute__((ext_vector_type(8))) __bf16 bf16x8;
typedef __attribute__((ext_vector_type(4))) float f32x4;

static __device__ __forceinline__ ushort f2bf(float x) {
    union { float f; unsigned u; } v; v.f = x;
    unsigned r = (v.u + 0x7FFFu + ((v.u >> 16) & 1u)) >> 16;
    return (ushort)r;
}

// ---------------- fp32 GEMM (encoder): C = [relu](A @ W + b) ----------------
// 128x128 tile, BK=8, 256 threads, 8x8 micro-tile in split-halves layout:
// rows {tm4..tm4+3, tm4+64..67}, cols {tn4..+3, tn4+64..67} -> conflict-free
// LDS reads (B: 256B-consecutive per instruction; A: broadcast groups).
template<bool RELU>
__global__ __launch_bounds__(256) void gemm_f32(
    const float* __restrict__ A, const float* __restrict__ W,
    const float* __restrict__ bias, float* __restrict__ C,
    int M, int K, int N)
{
    __shared__ float As[8][128];
    __shared__ float Bs[8][132];
    const int tid = threadIdx.x;
    const int bm = blockIdx.y << 7;
    const int bn = blockIdx.x << 7;

    const int la_row = tid >> 1;          // 0..127
    const int la_k   = (tid & 1) << 2;    // 0 or 4
    const int lb_row = tid >> 5;          // 0..7
    const int lb_col = (tid & 31) << 2;   // 0..124
    const int tm4 = (tid >> 4) << 2;      // 0..60
    const int tn4 = (tid & 15) << 2;      // 0..60

    float acc[8][8];
    #pragma unroll
    for (int i = 0; i < 8; ++i)
        #pragma unroll
        for (int j = 0; j < 8; ++j) acc[i][j] = 0.f;

    const float* aptr = A + (size_t)(bm + la_row) * K + la_k;
    const float* bptr = W + (size_t)lb_row * N + bn + lb_col;

    float4 av = *(const float4*)(aptr);
    float4 bv = *(const float4*)(bptr);

    for (int k0 = 0; k0 < K; k0 += 8) {
        __syncthreads();
        As[la_k + 0][la_row] = av.x;
        As[la_k + 1][la_row] = av.y;
        As[la_k + 2][la_row] = av.z;
        As[la_k + 3][la_row] = av.w;
        *(float4*)(&Bs[lb_row][lb_col]) = bv;
        __syncthreads();
        if (k0 + 8 < K) {   // prefetch next slab under the compute
            av = *(const float4*)(aptr + k0 + 8);
            bv = *(const float4*)(bptr + (size_t)(k0 + 8) * N);
        }
        #pragma unroll
        for (int kk = 0; kk < 8; ++kk) {
            float a[8], b[8];
            *(float4*)(a)     = *(const float4*)(&As[kk][tm4]);
            *(float4*)(a + 4) = *(const float4*)(&As[kk][tm4 + 64]);
            *(float4*)(b)     = *(const float4*)(&Bs[kk][tn4]);
            *(float4*)(b + 4) = *(const float4*)(&Bs[kk][tn4 + 64]);
            #pragma unroll
            for (int i = 0; i < 8; ++i)
                #pragma unroll
                for (int j = 0; j < 8; ++j)
                    acc[i][j] = fmaf(a[i], b[j], acc[i][j]);
        }
    }

    float bv0[8];
    #pragma unroll
    for (int j = 0; j < 8; ++j)
        bv0[j] = bias[bn + tn4 + (j < 4 ? j : 64 + j - 4)];

    #pragma unroll
    for (int i = 0; i < 8; ++i) {
        int row = bm + tm4 + (i < 4 ? i : 64 + i - 4);
        float* cp = C + (size_t)row * N + bn + tn4;
        float4 v0, v1;
        v0.x = acc[i][0] + bv0[0]; v0.y = acc[i][1] + bv0[1];
        v0.z = acc[i][2] + bv0[2]; v0.w = acc[i][3] + bv0[3];
        v1.x = acc[i][4] + bv0[4]; v1.y = acc[i][5] + bv0[5];
        v1.z = acc[i][6] + bv0[6]; v1.w = acc[i][7] + bv0[7];
        if (RELU) {
            v0.x = fmaxf(v0.x, 0.f); v0.y = fmaxf(v0.y, 0.f);
            v0.z = fmaxf(v0.z, 0.f); v0.w = fmaxf(v0.w, 0.f);
            v1.x = fmaxf(v1.x, 0.f); v1.y = fmaxf(v1.y, 0.f);
            v1.z = fmaxf(v1.z, 0.f); v1.w = fmaxf(v1.w, 0.f);
        }
        *(float4*)(cp) = v0;
        *(float4*)(cp + 64) = v1;
    }
}

// ---------------- bf16 MFMA GEMM (decoder) ----------------
// C[m][n] = [relu](sum_k A[m][k]*Wt[n][k] + b[n]).  128x128 tile, BK=64,
// 4 waves (2x2), 4x4 16x16x32 fragments per wave, global_load_lds(16B).
template<bool RELU, bool OUTF32>
__global__ __launch_bounds__(256) void gemm_bf16(
    const ushort* __restrict__ A,    // [M][K] bf16 bits
    const ushort* __restrict__ Wt,   // [N][K] bf16 bits (pre-transposed W)
    const float* __restrict__ bias,
    void* __restrict__ C,            // bf16 [M][N] or f32 [M][N]
    int M, int K, int N)
{
    __shared__ __align__(16) ushort As[128][64];
    __shared__ __align__(16) ushort Bs[128][64];
    const int tid  = threadIdx.x;
    const int lane = tid & 63;
    const int wv   = tid >> 6;
    const int wm   = (wv >> 1) << 6;   // 0 or 64
    const int wn   = (wv & 1) << 6;
    const int bm   = blockIdx.y << 7;
    const int bn   = blockIdx.x << 7;
    const int lr   = lane & 15;
    const int lh   = lane >> 4;        // 0..3

    f32x4 acc[4][4];
    #pragma unroll
    for (int m = 0; m < 4; ++m)
        #pragma unroll
        for (int n = 0; n < 4; ++n) acc[m][n] = (f32x4){0.f, 0.f, 0.f, 0.f};

    for (int k0 = 0; k0 < K; k0 += 64) {
        __syncthreads();
        #pragma unroll
        for (int i = 0; i < 4; ++i) {
            const int c    = wv * 4 + i;          // chunk 0..15 (8 rows each)
            const int boff = c * 1024 + lane * 16;
            const int r    = boff >> 7;           // tile row
            const int cb   = boff & 127;          // byte col within 128B row
            const char* sa = (const char*)A  + (((size_t)(bm + r) * K + k0) << 1) + cb;
            const char* sb = (const char*)Wt + (((size_t)(bn + r) * K + k0) << 1) + cb;
            __builtin_amdgcn_global_load_lds((const void*)sa, (void*)(&As[0][0] + c * 512), 16, 0, 0);
            __builtin_amdgcn_global_load_lds((const void*)sb, (void*)(&Bs[0][0] + c * 512), 16, 0, 0);
        }
        __syncthreads();
        #pragma unroll
        for (int kk = 0; kk < 64; kk += 32) {
            bf16x8 af[4], bfr[4];
            #pragma unroll
            for (int m = 0; m < 4; ++m)
                af[m] = *(const bf16x8*)&As[wm + m * 16 + lr][kk + lh * 8];
            #pragma unroll
            for (int n = 0; n < 4; ++n)
                bfr[n] = *(const bf16x8*)&Bs[wn + n * 16 + lr][kk + lh * 8];
            #pragma unroll
            for (int m = 0; m < 4; ++m)
                #pragma unroll
                for (int n = 0; n < 4; ++n)
                    acc[m][n] = __builtin_amdgcn_mfma_f32_16x16x32_bf16(
                        af[m], bfr[n], acc[m][n], 0, 0, 0);
        }
    }

    // epilogue: C/D mapping col = lane&15, row = (lane>>4)*4 + i
    #pragma unroll
    for (int n = 0; n < 4; ++n) {
        const int col = bn + wn + n * 16 + lr;
        const float bcol = bias[col];
        #pragma unroll
        for (int m = 0; m < 4; ++m) {
            #pragma unroll
            for (int i = 0; i < 4; ++i) {
                const int row = bm + wm + m * 16 + lh * 4 + i;
                float v = acc[m][n][i] + bcol;
                if (RELU) v = fmaxf(v, 0.f);
                if (OUTF32) ((float*)C)[(size_t)row * N + col] = v;
                else        ((ushort*)C)[(size_t)row * N + col] = f2bf(v);
            }
        }
    }
}

// ---------------- weight convert+transpose: W[K][N] f32 -> Wt[N][K] bf16 ----
__global__ __launch_bounds__(256) void wt_convert(
    const float* __restrict__ W, ushort* __restrict__ Wt, int K, int N)
{
    __shared__ ushort t[64][65];
    const int kb = blockIdx.y << 6, nb = blockIdx.x << 6;
    const int c  = threadIdx.x & 63;
    const int r0 = (threadIdx.x >> 6) << 4;
    #pragma unroll
    for (int i = 0; i < 16; ++i)
        t[r0 + i][c] = f2bf(W[(size_t)(kb + r0 + i) * N + nb + c]);
    __syncthreads();
    #pragma unroll
    for (int i = 0; i < 16; ++i)
        Wt[(size_t)(nb + r0 + i) * K + kb + c] = t[c][r0 + i];
}

// ---------------- codebook squared norms ----------------
__global__ __launch_bounds__(256) void cbsq_kernel(
    const float* __restrict__ cb, float* __restrict__ cbsq)
{
    int k = blockIdx.x * 256 + threadIdx.x;
    const float* r = cb + ((size_t)k << 7);
    float s = 0.f;
    #pragma unroll 8
    for (int d = 0; d < 128; ++d) s = fmaf(r[d], r[d], s);
    cbsq[k] = s;
}

// ---------------- residual quantization (fp32 exact path) ----------------
__global__ __launch_bounds__(256) void quant_kernel(
    const float* __restrict__ z, const float* __restrict__ cb,
    const float* __restrict__ cbsq, ushort* __restrict__ zhat_bf,
    float* __restrict__ codes)
{
    __shared__ float rs[16][128];
    __shared__ float cbl[64][132];
    __shared__ float cbsq_l[1024];

    const int tid  = threadIdx.x;
    const int lane = tid & 63;
    const int wv   = tid >> 6;
    const int row0 = blockIdx.x << 4;

    #pragma unroll
    for (int i = 0; i < 2; ++i) {
        int f = tid + (i << 8);
        ((float4*)rs)[f] = ((const float4*)(z + ((size_t)row0 << 7)))[f];
    }
    #pragma unroll
    for (int i = 0; i < 4; ++i) cbsq_l[tid + (i << 8)] = cbsq[tid + (i << 8)];
    __syncthreads();

    for (int t = 0; t < 3; ++t) {
        float rr_[4];
        #pragma unroll
        for (int j = 0; j < 4; ++j) {
            const float* rp = rs[wv * 4 + j];
            float v0 = rp[lane * 2], v1 = rp[lane * 2 + 1];
            float p = v0 * v0 + v1 * v1;
            #pragma unroll
            for (int off = 32; off >= 1; off >>= 1) p += __shfl_xor(p, off);
            rr_[j] = p;
        }

        float best_d[4] = {FLT_MAX_C, FLT_MAX_C, FLT_MAX_C, FLT_MAX_C};
        int   best_i[4] = {0, 0, 0, 0};

        for (int c = 0; c < 16; ++c) {
            __syncthreads();
            #pragma unroll
            for (int i = 0; i < 8; ++i) {
                int f    = tid + (i << 8);
                int code = f >> 5;
                int d4   = f & 31;
                float4 v = ((const float4*)(cb + ((size_t)(c * 64 + code) << 7)))[d4];
                *(float4*)(&cbl[code][d4 << 2]) = v;
            }
            __syncthreads();

            const int k = c * 64 + lane;
            float acc0 = 0.f, acc1 = 0.f, acc2 = 0.f, acc3 = 0.f;
            #pragma unroll 8
            for (int d4 = 0; d4 < 32; ++d4) {
                float4 cv = *(const float4*)(&cbl[lane][d4 << 2]);
                float4 r0 = *(const float4*)(&rs[wv * 4 + 0][d4 << 2]);
                float4 r1 = *(const float4*)(&rs[wv * 4 + 1][d4 << 2]);
                float4 r2 = *(const float4*)(&rs[wv * 4 + 2][d4 << 2]);
                float4 r3 = *(const float4*)(&rs[wv * 4 + 3][d4 << 2]);
                acc0 = fmaf(r0.x, cv.x, acc0); acc0 = fmaf(r0.y, cv.y, acc0);
                acc0 = fmaf(r0.z, cv.z, acc0); acc0 = fmaf(r0.w, cv.w, acc0);
                acc1 = fmaf(r1.x, cv.x, acc1); acc1 = fmaf(r1.y, cv.y, acc1);
                acc1 = fmaf(r1.z, cv.z, acc1); acc1 = fmaf(r1.w, cv.w, acc1);
                acc2 = fmaf(r2.x, cv.x, acc2); acc2 = fmaf(r2.y, cv.y, acc2);
                acc2 = fmaf(r2.z, cv.z, acc2); acc2 = fmaf(r2.w, cv.w, acc2);
                acc3 = fmaf(r3.x, cv.x, acc3); acc3 = fmaf(r3.y, cv.y, acc3);
                acc3 = fmaf(r3.z, cv.z, acc3); acc3 = fmaf(r3.w, cv.w, acc3);
            }
            float dd[4];
            dd[0] = (rr_[0] + cbsq_l[k]) - 2.f * acc0;
            dd[1] = (rr_[1] + cbsq_l[k]) - 2.f * acc1;
            dd[2] = (rr_[2] + cbsq_l[k]) - 2.f * acc2;
            dd[3] = (rr_[3] + cbsq_l[k]) - 2.f * acc3;
            #pragma unroll
            for (int j = 0; j < 4; ++j)
                if (dd[j] < best_d[j]) { best_d[j] = dd[j]; best_i[j] = k; }
        }

        #pragma unroll
        for (int j = 0; j < 4; ++j) {
            float d = best_d[j]; int bi = best_i[j];
            #pragma unroll
            for (int off = 32; off >= 1; off >>= 1) {
                float od = __shfl_xor(d, off);
                int   oi = __shfl_xor(bi, off);
                if (od < d || (od == d && oi < bi)) { d = od; bi = oi; }
            }
            best_d[j] = d; best_i[j] = bi;
        }

        #pragma unroll
        for (int j = 0; j < 4; ++j) {
            int row = row0 + wv * 4 + j;
            if (lane == 0) codes[(size_t)row * 3 + t] = (float)best_i[j];
            const float* cvec = cb + ((size_t)best_i[j] << 7);
            rs[wv * 4 + j][lane * 2]     -= cvec[lane * 2];
            rs[wv * 4 + j][lane * 2 + 1] -= cvec[lane * 2 + 1];
        }
    }

    __syncthreads();
    #pragma unroll
    for (int i = 0; i < 2; ++i) {
        int f = tid + (i << 8);
        float4 zv = ((const float4*)(z + ((size_t)row0 << 7)))[f];
        float4 rv = ((float4*)rs)[f];
        ushort4 o;
        o.x = f2bf(zv.x - rv.x); o.y = f2bf(zv.y - rv.y);
        o.z = f2bf(zv.z - rv.z); o.w = f2bf(zv.w - rv.w);
        ((ushort4*)(zhat_bf + ((size_t)row0 << 7)))[f] = o;
    }
}

extern "C" void kernel_launch(void* const* d_in, const int* in_sizes, int n_in,
                              void* d_out, int out_size, void* d_ws, size_t ws_size,
                              hipStream_t stream)
{
    const float* x   = (const float*)d_in[0];
    const float* eW1 = (const float*)d_in[1];
    const float* eb1 = (const float*)d_in[2];
    const float* eW2 = (const float*)d_in[3];
    const float* eb2 = (const float*)d_in[4];
    const float* eW3 = (const float*)d_in[5];
    const float* eb3 = (const float*)d_in[6];
    const float* eW4 = (const float*)d_in[7];
    const float* eb4 = (const float*)d_in[8];
    const float* dW1 = (const float*)d_in[9];
    const float* db1 = (const float*)d_in[10];
    const float* dW2 = (const float*)d_in[11];
    const float* db2 = (const float*)d_in[12];
    const float* dW3 = (const float*)d_in[13];
    const float* db3 = (const float*)d_in[14];
    const float* dW4 = (const float*)d_in[15];
    const float* db4 = (const float*)d_in[16];
    const float* cb  = (const float*)d_in[17];

    float* out   = (float*)d_out;
    float* codes = out + (size_t)32768 * 768;

    // ---- workspace layout: [dec Wt bf16 | cbsq | per-chunk activations] ----
    ushort* Wt1 = (ushort*)d_ws;                       // 2048 x 128
    ushort* Wt2 = Wt1 + (size_t)2048 * 128;            // 1024 x 2048
    ushort* Wt3 = Wt2 + (size_t)1024 * 2048;           // 512 x 1024
    ushort* Wt4 = Wt3 + (size_t)512 * 1024;            // 768 x 512
    float*  sq  = (float*)(Wt4 + (size_t)768 * 512);   // 1024
    float*  act = sq + 1024;
    const size_t fixed_b = (char*)act - (char*)d_ws;   // 6,557,696 B

    int mc = 32768;                                    // chunk rows
    while (mc > 1024) {
        if (fixed_b + (size_t)mc * 15104 <= ws_size) break;
        mc >>= 1;
    }

    float*  R1  = act;                         // mc x 2048 f32
    float*  R2  = R1 + (size_t)mc * 2048;      // mc x 1024 f32
    float*  R3  = R2 + (size_t)mc * 1024;      // mc x 512  f32
    float*  RZ  = R3 + (size_t)mc * 512;       // mc x 128  f32
    ushort* ZHb = (ushort*)(RZ + (size_t)mc * 128);  // mc x 128 bf16
    ushort* D1  = (ushort*)R1;                 // mc x 2048 bf16 (aliases R1)
    ushort* D2  = (ushort*)R2;                 // mc x 1024 bf16
    ushort* D3  = (ushort*)R3;                 // mc x 512  bf16

    // one-time per-launch prep
    wt_convert<<<dim3(2048 / 64, 128 / 64), 256, 0, stream>>>(dW1, Wt1, 128, 2048);
    wt_convert<<<dim3(1024 / 64, 2048 / 64), 256, 0, stream>>>(dW2, Wt2, 2048, 1024);
    wt_convert<<<dim3(512 / 64, 1024 / 64), 256, 0, stream>>>(dW3, Wt3, 1024, 512);
    wt_convert<<<dim3(768 / 64, 512 / 64), 256, 0, stream>>>(dW4, Wt4, 512, 768);
    cbsq_kernel<<<4, 256, 0, stream>>>(cb, sq);

    const int mg = mc >> 7;
    for (int r0 = 0; r0 < 32768; r0 += mc) {
        const float* xi     = x     + (size_t)r0 * 768;
        float*       outi   = out   + (size_t)r0 * 768;
        float*       codesi = codes + (size_t)r0 * 3;
        // encoder (fp32 exact-class: codes depend on z)
        gemm_f32<true ><<<dim3(16, mg), 256, 0, stream>>>(xi, eW1, eb1, R1, mc, 768,  2048);
        gemm_f32<true ><<<dim3( 8, mg), 256, 0, stream>>>(R1, eW2, eb2, R2, mc, 2048, 1024);
        gemm_f32<true ><<<dim3( 4, mg), 256, 0, stream>>>(R2, eW3, eb3, R3, mc, 1024, 512);
        gemm_f32<false><<<dim3( 1, mg), 256, 0, stream>>>(R3, eW4, eb4, RZ, mc, 512,  128);
        // residual quantization (fp32), emits bf16 z_hat
        quant_kernel<<<mc >> 4, 256, 0, stream>>>(RZ, cb, sq, ZHb, codesi);
        // decoder in bf16 MFMA (tolerance is generous)
        gemm_bf16<true , false><<<dim3(16, mg), 256, 0, stream>>>(ZHb, Wt1, db1, D1,   mc, 128,  2048);
        gemm_bf16<true , false><<<dim3( 8, mg), 256, 0, stream>>>(D1,  Wt2, db2, D2,   mc, 2048, 1024);
        gemm_bf16<true , false><<<dim3( 4, mg), 256, 0, stream>>>(D2,  Wt3, db3, D3,   mc, 1024, 512);
        gemm_bf16<false, true ><<<dim3( 6, mg), 256, 0, stream>>>(D3,  Wt4, db4, outi, mc, 512,  768);
    }
}